// Round 1
// baseline (274.785 us; speedup 1.0000x reference)
//
#include <hip/hip_runtime.h>

// Problem constants (fixed by reference)
#define BB 8
#define NN 128
#define CC 64
static constexpr float INV_A = 1.0f / 49.0f;   // average_nobj = 49.0

// Workspace layout (float offsets)
#define OFF_C    0           // C[b][d][s], 15*64*64
#define OFF_C3T  61440       // C3^T [s][d]
#define OFF_C4T  65536       // C4^T [s][d]
#define OFF_RS   69632       // rowsum/A  [n][i][d]
#define OFF_CS   135168      // colsum/A  [n][j][d]
#define OFF_DV   200704      // diag      [n][i][d]
#define OFF_TR   266240      // trace/A   [n][d]
#define OFF_AS   266752      // allsum/A^2[n][d]
#define OFF_U1   267264      // U1 + S + bias      [n][i][s]
#define OFF_U2   332800      // U2                 [n][j][s]
#define OFF_DG   398336      // diag term + dbias  [n][i][s]
// total 463872 floats = 1.86 MB

// ---------------------------------------------------------------------------
// K0: build coefficient matrices C[b][d][s] = c00[d,b]*c10[d,s] + c01[s,b]*c11[d,s]
// plus transposed copies of C3, C4 in [s][d] layout for the main GEMM.
__global__ void k_coefs(const float* __restrict__ c00, const float* __restrict__ c01,
                        const float* __restrict__ c10, const float* __restrict__ c11,
                        float* __restrict__ ws) {
    int idx = blockIdx.x * 256 + threadIdx.x;
    if (idx < 15 * 4096) {
        int b = idx >> 12; int r = idx & 4095; int d = r >> 6; int s = r & 63;
        ws[OFF_C + idx] = c00[d * 15 + b] * c10[d * 64 + s] + c01[s * 15 + b] * c11[d * 64 + s];
    } else if (idx < 15 * 4096 + 8192) {
        int k = idx - 15 * 4096;
        int which = k >> 12;               // 0 -> b=3 (identity), 1 -> b=4 (transpose)
        int r = k & 4095; int s = r >> 6; int d = r & 63;
        int b = 3 + which;
        float v = c00[d * 15 + b] * c10[d * 64 + s] + c01[s * 15 + b] * c11[d * 64 + s];
        ws[(which ? OFF_C4T : OFF_C3T) + s * 64 + d] = v;
    }
}

// ---------------------------------------------------------------------------
// K1: row sums (+ diagonal capture) and column sums.
// grid 512: blocks [0,256) rowsum, [256,512) colsum. 256 threads:
// (q = j-quarter, ii = row-in-tile, d4 = float4 channel group)
__global__ void k_reduce(const float* __restrict__ in, float* __restrict__ ws) {
    __shared__ float4 part[4][4][16];
    int mode = blockIdx.x >> 8;            // 0 rowsum, 1 colsum
    int bb = blockIdx.x & 255;
    int n = bb >> 5; int g0 = (bb & 31) * 4;
    int t = threadIdx.x;
    int q = t >> 6; int ii = (t >> 4) & 3; int d4 = t & 15;
    float4 acc = make_float4(0.f, 0.f, 0.f, 0.f);
    if (mode == 0) {
        int i = g0 + ii;
        float4 dvv = acc; bool hd = false;
        const float* base = in + ((size_t)(n * NN + i)) * NN * CC + d4 * 4;
        for (int j = q * 32; j < q * 32 + 32; ++j) {
            float4 v = *(const float4*)(base + (size_t)j * CC);
            acc.x += v.x; acc.y += v.y; acc.z += v.z; acc.w += v.w;
            if (j == i) { dvv = v; hd = true; }
        }
        if (hd) *(float4*)(ws + OFF_DV + ((size_t)(n * NN + i)) * CC + d4 * 4) = dvv;
    } else {
        int j = g0 + ii;
        for (int i = q * 32; i < q * 32 + 32; ++i) {
            float4 v = *(const float4*)(in + (((size_t)(n * NN + i)) * NN + j) * CC + d4 * 4);
            acc.x += v.x; acc.y += v.y; acc.z += v.z; acc.w += v.w;
        }
    }
    part[q][ii][d4] = acc;
    __syncthreads();
    if (t < 64) {
        int i2 = t >> 4; int dd = t & 15;
        float4 a = part[0][i2][dd], b = part[1][i2][dd], c = part[2][i2][dd], d = part[3][i2][dd];
        float4 s;
        s.x = (a.x + b.x + c.x + d.x) * INV_A;
        s.y = (a.y + b.y + c.y + d.y) * INV_A;
        s.z = (a.z + b.z + c.z + d.z) * INV_A;
        s.w = (a.w + b.w + c.w + d.w) * INV_A;
        *(float4*)(ws + (mode ? OFF_CS : OFF_RS) + ((size_t)(n * NN + g0 + i2)) * CC + dd * 4) = s;
    }
}

// ---------------------------------------------------------------------------
// K2: trace/A and allsum/A^2 per (n, d). rs already has one /A factor.
__global__ void k_traces(float* __restrict__ ws) {
    int n = blockIdx.x; int d = threadIdx.x;
    float tr = 0.f, as = 0.f;
    for (int i = 0; i < NN; ++i) {
        tr += ws[OFF_DV + ((size_t)(n * NN + i)) * CC + d];
        as += ws[OFF_RS + ((size_t)(n * NN + i)) * CC + d];
    }
    ws[OFF_TR + n * CC + d] = tr * INV_A;
    ws[OFF_AS + n * CC + d] = as * INV_A;
}

// ---------------------------------------------------------------------------
// K3: small per-(n,i) GEMMs over d for the broadcast terms.
// U1[i,s] = sum_d C1*dv + C9*rs + C11*cs   (+ S[n,s] + bias)
// U2[j,s] = sum_d C2*dv + C10*rs + C12*cs
// DG[i,s] = sum_d C0*dv + C5*rs + C6*cs + C7*tr + C8*as   (+ diag_bias)
// S[n,s]  = sum_d C13*tr + C14*as
// block = (n, 4 i rows), 64 threads = s.
__global__ void k_uv(const float* __restrict__ bias, const float* __restrict__ dbias,
                     float* __restrict__ ws) {
    int n = blockIdx.x >> 5; int i0 = (blockIdx.x & 31) * 4; int s = threadIdx.x;
    const float* C = ws + OFF_C;
    float aU1[4] = {0, 0, 0, 0}, aU2[4] = {0, 0, 0, 0}, aDG[4] = {0, 0, 0, 0};
    float aS = 0.f, aDGc = 0.f;
    for (int dc = 0; dc < 16; ++dc) {
        float tr4[4], as4[4], dv4[4][4], rs4[4][4], cs4[4][4];
        {
            float4 v = *(const float4*)(ws + OFF_TR + n * CC + dc * 4);
            tr4[0] = v.x; tr4[1] = v.y; tr4[2] = v.z; tr4[3] = v.w;
            float4 w = *(const float4*)(ws + OFF_AS + n * CC + dc * 4);
            as4[0] = w.x; as4[1] = w.y; as4[2] = w.z; as4[3] = w.w;
        }
        #pragma unroll
        for (int ii = 0; ii < 4; ++ii) {
            size_t ro = ((size_t)(n * NN + i0 + ii)) * CC + dc * 4;
            float4 v = *(const float4*)(ws + OFF_DV + ro);
            dv4[ii][0] = v.x; dv4[ii][1] = v.y; dv4[ii][2] = v.z; dv4[ii][3] = v.w;
            float4 r = *(const float4*)(ws + OFF_RS + ro);
            rs4[ii][0] = r.x; rs4[ii][1] = r.y; rs4[ii][2] = r.z; rs4[ii][3] = r.w;
            float4 c = *(const float4*)(ws + OFF_CS + ro);
            cs4[ii][0] = c.x; cs4[ii][1] = c.y; cs4[ii][2] = c.z; cs4[ii][3] = c.w;
        }
        #pragma unroll
        for (int k = 0; k < 4; ++k) {
            int d = dc * 4 + k;
            const float* Cd = C + d * 64 + s;
            float c0 = Cd[0 * 4096], c1 = Cd[1 * 4096], c2 = Cd[2 * 4096];
            float c5 = Cd[5 * 4096], c6 = Cd[6 * 4096], c7 = Cd[7 * 4096];
            float c8 = Cd[8 * 4096], c9 = Cd[9 * 4096], c10v = Cd[10 * 4096];
            float c11v = Cd[11 * 4096], c12v = Cd[12 * 4096];
            float c13 = Cd[13 * 4096], c14 = Cd[14 * 4096];
            aS += c13 * tr4[k] + c14 * as4[k];
            aDGc += c7 * tr4[k] + c8 * as4[k];
            #pragma unroll
            for (int ii = 0; ii < 4; ++ii) {
                aU1[ii] += c1 * dv4[ii][k] + c9 * rs4[ii][k] + c11v * cs4[ii][k];
                aU2[ii] += c2 * dv4[ii][k] + c10v * rs4[ii][k] + c12v * cs4[ii][k];
                aDG[ii] += c0 * dv4[ii][k] + c5 * rs4[ii][k] + c6 * cs4[ii][k];
            }
        }
    }
    float bs = bias[s], dbs = dbias[s];
    for (int ii = 0; ii < 4; ++ii) {
        size_t row = ((size_t)(n * NN + i0 + ii)) * CC + s;
        ws[OFF_U1 + row] = aU1[ii] + aS + bs;
        ws[OFF_U2 + row] = aU2[ii];
        ws[OFF_DG + row] = aDG[ii] + aDGc + dbs;
    }
}

// ---------------------------------------------------------------------------
// K4: main kernel. Block tile = 64 pixels (fixed n,i; j in [j0,j0+64)) x 64 s.
// Two K=64 passes (x_ij*C3, x_ji*C4) into shared 4x4 register accumulators.
// LDS rows padded to 68 floats; s-mapping s = ss*16+ts keeps ds_read_b128
// aliasing at <=2-way (free).
__global__ __launch_bounds__(256, 2) void k_main(
        const float* __restrict__ in, const float* __restrict__ mask,
        const float* __restrict__ ws, float* __restrict__ out) {
    __shared__ __align__(16) float xbuf[64 * 68];
    __shared__ __align__(16) float cbuf[64 * 68];
    int blk = blockIdx.x;
    int n = blk >> 8; int rem = blk & 255; int i = rem >> 1; int j0 = (rem & 1) * 64;
    int t = threadIdx.x;
    int tp = t >> 4; int ts = t & 15;
    float acc[4][4];
    #pragma unroll
    for (int a = 0; a < 4; ++a)
        #pragma unroll
        for (int b = 0; b < 4; ++b) acc[a][b] = 0.f;

    for (int pass = 0; pass < 2; ++pass) {
        const float* csrc = ws + (pass ? OFF_C4T : OFF_C3T);
        #pragma unroll
        for (int r = 0; r < 4; ++r) {
            int idx = t + r * 256;
            int p = idx >> 4; int c = idx & 15;
            size_t gaddr;
            if (pass == 0) gaddr = (((size_t)(n * NN + i)) * NN + (j0 + p)) * CC + c * 4;
            else           gaddr = (((size_t)(n * NN + (j0 + p))) * NN + i) * CC + c * 4;
            float4 v = *(const float4*)(in + gaddr);
            *(float4*)&xbuf[p * 68 + c * 4] = v;
            float4 cvv = *(const float4*)(csrc + p * 64 + c * 4);
            *(float4*)&cbuf[p * 68 + c * 4] = cvv;
        }
        __syncthreads();
        #pragma unroll
        for (int dc = 0; dc < 16; ++dc) {
            float4 xv[4], cv[4];
            #pragma unroll
            for (int pp = 0; pp < 4; ++pp)
                xv[pp] = *(const float4*)&xbuf[(tp * 4 + pp) * 68 + dc * 4];
            #pragma unroll
            for (int ss = 0; ss < 4; ++ss)
                cv[ss] = *(const float4*)&cbuf[(ss * 16 + ts) * 68 + dc * 4];
            #pragma unroll
            for (int pp = 0; pp < 4; ++pp)
                #pragma unroll
                for (int ss = 0; ss < 4; ++ss)
                    acc[pp][ss] += xv[pp].x * cv[ss].x + xv[pp].y * cv[ss].y
                                 + xv[pp].z * cv[ss].z + xv[pp].w * cv[ss].w;
        }
        __syncthreads();
    }

    // epilogue: + U1[i] + U2[j] + (i==j)DG[i], leaky relu, mask
    int srow = (n * NN + i) * CC;
    float u1[4];
    #pragma unroll
    for (int ss = 0; ss < 4; ++ss) u1[ss] = ws[OFF_U1 + srow + ss * 16 + ts];
    #pragma unroll
    for (int pp = 0; pp < 4; ++pp) {
        int j = j0 + tp * 4 + pp;
        float m = mask[(size_t)(n * NN + i) * NN + j];
        size_t orow = ((size_t)(n * NN + i) * NN + j) * (size_t)CC;
        int u2row = (n * NN + j) * CC;
        bool diag = (i == j);
        #pragma unroll
        for (int ss = 0; ss < 4; ++ss) {
            int s = ss * 16 + ts;
            float v = acc[pp][ss] + u1[ss] + ws[OFF_U2 + u2row + s];
            if (diag) v += ws[OFF_DG + srow + s];
            v = v > 0.f ? v : 0.01f * v;
            out[orow + s] = v * m;
        }
    }
}

// ---------------------------------------------------------------------------
extern "C" void kernel_launch(void* const* d_in, const int* in_sizes, int n_in,
                              void* d_out, int out_size, void* d_ws, size_t ws_size,
                              hipStream_t stream) {
    const float* inputs = (const float*)d_in[0];
    const float* mask   = (const float*)d_in[1];
    // d_in[2] = nobj (unused by the reference computation)
    const float* c00 = (const float*)d_in[3];
    const float* c01 = (const float*)d_in[4];
    const float* c10 = (const float*)d_in[5];
    const float* c11 = (const float*)d_in[6];
    const float* bias  = (const float*)d_in[7];
    const float* dbias = (const float*)d_in[8];
    float* out = (float*)d_out;
    float* ws = (float*)d_ws;

    k_coefs <<<272, 256, 0, stream>>>(c00, c01, c10, c11, ws);
    k_reduce<<<512, 256, 0, stream>>>(inputs, ws);
    k_traces<<<8, 64, 0, stream>>>(ws);
    k_uv    <<<256, 64, 0, stream>>>(bias, dbias, ws);
    k_main  <<<2048, 256, 0, stream>>>(inputs, mask, ws, out);
}

// Round 2
// 151.040 us; speedup vs baseline: 1.8193x; 1.8193x over previous
//
#include <hip/hip_runtime.h>

// Problem constants (fixed by reference)
#define BB 8
#define NN 128
#define CC 64
static constexpr float INV_A = 1.0f / 49.0f;   // average_nobj = 49.0

// Workspace layout (float offsets)
#define OFF_C    0           // C[b][d][s], 15*64*64 fp32 (for k_uv)
#define OFF_CB   61440       // Cb bf16 [s][k=128]: k<64 -> C3[d][s], k>=64 -> C4[d][s]
#define OFF_RS   65536       // rowsum/A  [n][i][d]
#define OFF_CS   131072      // colsum/A  [n][j][d]
#define OFF_DV   196608      // diag      [n][i][d]
#define OFF_TR   262144      // trace/A   [n][d]
#define OFF_AS   262656      // allsum/A^2[n][d]
#define OFF_U1   263168      // U1 + S + bias      [n][i][s]
#define OFF_U2   328704      // U2                 [n][j][s]
#define OFF_DG   394240      // diag term + dbias  [n][i][s]
// total 459776 floats = 1.84 MB

typedef __attribute__((ext_vector_type(8))) short v8s;
typedef __attribute__((ext_vector_type(4))) float v4f;

// pack two fp32 -> one dword of two bf16 (round-half-up; err <= 2^-9 rel)
static __device__ inline unsigned pack2bf(float a, float b) {
    union { float f; unsigned u; } ua, ub; ua.f = a; ub.f = b;
    return ((ua.u + 0x8000u) >> 16) | ((ub.u + 0x8000u) & 0xffff0000u);
}
static __device__ inline unsigned short f2bf(float a) {
    union { float f; unsigned u; } ua; ua.f = a;
    return (unsigned short)((ua.u + 0x8000u) >> 16);
}

// ---------------------------------------------------------------------------
// K0: C[b][d][s] = c00[d,b]*c10[d,s] + c01[s,b]*c11[d,s]  (fp32, for k_uv)
// plus Cb bf16 [s][128] = [C3^T | C4^T] for the MFMA GEMM.
__global__ void k_coefs(const float* __restrict__ c00, const float* __restrict__ c01,
                        const float* __restrict__ c10, const float* __restrict__ c11,
                        float* __restrict__ ws) {
    int idx = blockIdx.x * 256 + threadIdx.x;
    if (idx < 15 * 4096) {
        int b = idx >> 12; int r = idx & 4095; int d = r >> 6; int s = r & 63;
        ws[OFF_C + idx] = c00[d * 15 + b] * c10[d * 64 + s] + c01[s * 15 + b] * c11[d * 64 + s];
    } else if (idx < 15 * 4096 + 8192) {
        int k = idx - 15 * 4096;
        int which = k >> 12;               // 0 -> b=3 (identity), 1 -> b=4 (transpose)
        int r = k & 4095; int s = r >> 6; int d = r & 63;
        int b = 3 + which;
        float v = c00[d * 15 + b] * c10[d * 64 + s] + c01[s * 15 + b] * c11[d * 64 + s];
        unsigned short* cb = (unsigned short*)(ws + OFF_CB);
        cb[s * 128 + which * 64 + d] = f2bf(v);
    }
}

// ---------------------------------------------------------------------------
// K1: row sums (+ diagonal capture) and column sums (unchanged from R1).
__global__ void k_reduce(const float* __restrict__ in, float* __restrict__ ws) {
    __shared__ float4 part[4][4][16];
    int mode = blockIdx.x >> 8;            // 0 rowsum, 1 colsum
    int bb = blockIdx.x & 255;
    int n = bb >> 5; int g0 = (bb & 31) * 4;
    int t = threadIdx.x;
    int q = t >> 6; int ii = (t >> 4) & 3; int d4 = t & 15;
    float4 acc = make_float4(0.f, 0.f, 0.f, 0.f);
    if (mode == 0) {
        int i = g0 + ii;
        float4 dvv = acc; bool hd = false;
        const float* base = in + ((size_t)(n * NN + i)) * NN * CC + d4 * 4;
        for (int j = q * 32; j < q * 32 + 32; ++j) {
            float4 v = *(const float4*)(base + (size_t)j * CC);
            acc.x += v.x; acc.y += v.y; acc.z += v.z; acc.w += v.w;
            if (j == i) { dvv = v; hd = true; }
        }
        if (hd) *(float4*)(ws + OFF_DV + ((size_t)(n * NN + i)) * CC + d4 * 4) = dvv;
    } else {
        int j = g0 + ii;
        for (int i = q * 32; i < q * 32 + 32; ++i) {
            float4 v = *(const float4*)(in + (((size_t)(n * NN + i)) * NN + j) * CC + d4 * 4);
            acc.x += v.x; acc.y += v.y; acc.z += v.z; acc.w += v.w;
        }
    }
    part[q][ii][d4] = acc;
    __syncthreads();
    if (t < 64) {
        int i2 = t >> 4; int dd = t & 15;
        float4 a = part[0][i2][dd], b = part[1][i2][dd], c = part[2][i2][dd], d = part[3][i2][dd];
        float4 s;
        s.x = (a.x + b.x + c.x + d.x) * INV_A;
        s.y = (a.y + b.y + c.y + d.y) * INV_A;
        s.z = (a.z + b.z + c.z + d.z) * INV_A;
        s.w = (a.w + b.w + c.w + d.w) * INV_A;
        *(float4*)(ws + (mode ? OFF_CS : OFF_RS) + ((size_t)(n * NN + g0 + i2)) * CC + dd * 4) = s;
    }
}

// ---------------------------------------------------------------------------
// K2: trace/A and allsum/A^2 per (n,d). Coalesced reads + LDS reduce.
__global__ void k_traces(float* __restrict__ ws) {
    __shared__ float pt[4][64], pa[4][64];
    int n = blockIdx.x; int t = threadIdx.x;
    int d = t & 63; int q = t >> 6;
    float tr = 0.f, as = 0.f;
    for (int e = 0; e < 32; ++e) {
        int i = q * 32 + e;
        tr += ws[OFF_DV + ((size_t)(n * NN + i)) * CC + d];
        as += ws[OFF_RS + ((size_t)(n * NN + i)) * CC + d];
    }
    pt[q][d] = tr; pa[q][d] = as;
    __syncthreads();
    if (t < 64) {
        float T = pt[0][t] + pt[1][t] + pt[2][t] + pt[3][t];
        float A2 = pa[0][t] + pa[1][t] + pa[2][t] + pa[3][t];
        ws[OFF_TR + n * CC + t] = T * INV_A;
        ws[OFF_AS + n * CC + t] = A2 * INV_A;
    }
}

// ---------------------------------------------------------------------------
// K3: broadcast-term GEMMs (unchanged from R1 — validated).
__global__ void k_uv(const float* __restrict__ bias, const float* __restrict__ dbias,
                     float* __restrict__ ws) {
    int n = blockIdx.x >> 5; int i0 = (blockIdx.x & 31) * 4; int s = threadIdx.x;
    const float* C = ws + OFF_C;
    float aU1[4] = {0, 0, 0, 0}, aU2[4] = {0, 0, 0, 0}, aDG[4] = {0, 0, 0, 0};
    float aS = 0.f, aDGc = 0.f;
    for (int dc = 0; dc < 16; ++dc) {
        float tr4[4], as4[4], dv4[4][4], rs4[4][4], cs4[4][4];
        {
            float4 v = *(const float4*)(ws + OFF_TR + n * CC + dc * 4);
            tr4[0] = v.x; tr4[1] = v.y; tr4[2] = v.z; tr4[3] = v.w;
            float4 w = *(const float4*)(ws + OFF_AS + n * CC + dc * 4);
            as4[0] = w.x; as4[1] = w.y; as4[2] = w.z; as4[3] = w.w;
        }
        #pragma unroll
        for (int ii = 0; ii < 4; ++ii) {
            size_t ro = ((size_t)(n * NN + i0 + ii)) * CC + dc * 4;
            float4 v = *(const float4*)(ws + OFF_DV + ro);
            dv4[ii][0] = v.x; dv4[ii][1] = v.y; dv4[ii][2] = v.z; dv4[ii][3] = v.w;
            float4 r = *(const float4*)(ws + OFF_RS + ro);
            rs4[ii][0] = r.x; rs4[ii][1] = r.y; rs4[ii][2] = r.z; rs4[ii][3] = r.w;
            float4 c = *(const float4*)(ws + OFF_CS + ro);
            cs4[ii][0] = c.x; cs4[ii][1] = c.y; cs4[ii][2] = c.z; cs4[ii][3] = c.w;
        }
        #pragma unroll
        for (int k = 0; k < 4; ++k) {
            int d = dc * 4 + k;
            const float* Cd = C + d * 64 + s;
            float c0 = Cd[0 * 4096], c1 = Cd[1 * 4096], c2 = Cd[2 * 4096];
            float c5 = Cd[5 * 4096], c6 = Cd[6 * 4096], c7 = Cd[7 * 4096];
            float c8 = Cd[8 * 4096], c9 = Cd[9 * 4096], c10v = Cd[10 * 4096];
            float c11v = Cd[11 * 4096], c12v = Cd[12 * 4096];
            float c13 = Cd[13 * 4096], c14 = Cd[14 * 4096];
            aS += c13 * tr4[k] + c14 * as4[k];
            aDGc += c7 * tr4[k] + c8 * as4[k];
            #pragma unroll
            for (int ii = 0; ii < 4; ++ii) {
                aU1[ii] += c1 * dv4[ii][k] + c9 * rs4[ii][k] + c11v * cs4[ii][k];
                aU2[ii] += c2 * dv4[ii][k] + c10v * rs4[ii][k] + c12v * cs4[ii][k];
                aDG[ii] += c0 * dv4[ii][k] + c5 * rs4[ii][k] + c6 * cs4[ii][k];
            }
        }
    }
    float bs = bias[s], dbs = dbias[s];
    for (int ii = 0; ii < 4; ++ii) {
        size_t row = ((size_t)(n * NN + i0 + ii)) * CC + s;
        ws[OFF_U1 + row] = aU1[ii] + aS + bs;
        ws[OFF_U2 + row] = aU2[ii];
        ws[OFF_DG + row] = aDG[ii] + aDGc + dbs;
    }
}

// ---------------------------------------------------------------------------
// K4: MFMA main kernel. Block = (n, i, j-half): 64 pixels x 64 s, K=128.
// A[p][k] bf16 in LDS: k<64 = x[n,i,j0+p,:], k>=64 = x[n,j0+p,i,:].
// B[s][k] bf16 in LDS (from ws Cb). 4 waves, one 16-row M-tile each,
// 4 s-tiles x 4 K-steps = 16 MFMA (16x16x32 bf16) per wave.
// Epilogue: acc -> LDS (reusing A buffer) -> float4 coalesced stores.
__global__ __launch_bounds__(256, 4) void k_main(
        const float* __restrict__ in, const float* __restrict__ mask,
        const float* __restrict__ ws, float* __restrict__ out) {
    __shared__ __align__(16) unsigned char smem[34816 + 17408];
    unsigned short* Ab = (unsigned short*)smem;            // 64 x 136 bf16 (pad 8)... rows*272B
    unsigned short* Bb = (unsigned short*)(smem + 17408);  // 64 x 136 bf16
    float* Obuf = (float*)smem;                            // epilogue: 64 x 68 fp32 = 17408 B

    int blk = blockIdx.x;
    int n = blk >> 8; int rem = blk & 255; int i = rem >> 1; int j0 = (rem & 1) * 64;
    int t = threadIdx.x;
    int tp = t >> 4; int c = t & 15;       // c constant per thread (256 % 16 == 0)

    // ---- stage B: 64x128 bf16 from ws Cb (16 KB, L2-hot) ----
    const unsigned short* cb = (const unsigned short*)(ws + OFF_CB);
    {
        int cc8 = t & 15;                   // 16-byte chunk (8 bf16) within row
        #pragma unroll
        for (int e = 0; e < 4; ++e) {
            int s = e * 16 + tp;
            float4 v = *(const float4*)(cb + s * 128 + cc8 * 8);   // raw 16B copy
            *(float4*)((unsigned char*)(Bb + s * 136 + cc8 * 8)) = v;
        }
    }
    // ---- stage A row-half: x[n,i,j0..j0+64,:] fp32 -> bf16 ----
    {
        const float* src = in + (((size_t)(n * NN + i)) * NN + j0) * CC;
        #pragma unroll
        for (int e = 0; e < 4; ++e) {
            int p = e * 16 + tp;
            float4 v = *(const float4*)(src + (size_t)p * CC + c * 4);
            uint2 pk; pk.x = pack2bf(v.x, v.y); pk.y = pack2bf(v.z, v.w);
            *(uint2*)(Ab + p * 136 + c * 4) = pk;
        }
    }
    // ---- stage A col-half: x[n,j0+p,i,:] fp32 -> bf16 ----
    {
        #pragma unroll
        for (int e = 0; e < 4; ++e) {
            int p = e * 16 + tp;
            const float* src = in + (((size_t)(n * NN + (j0 + p))) * NN + i) * CC;
            float4 v = *(const float4*)(src + c * 4);
            uint2 pk; pk.x = pack2bf(v.x, v.y); pk.y = pack2bf(v.z, v.w);
            *(uint2*)(Ab + p * 136 + 64 + c * 4) = pk;
        }
    }
    __syncthreads();

    // ---- MFMA compute ----
    int w = t >> 6; int l = t & 63;
    int r16 = l & 15; int quad = l >> 4;
    v4f acc[4];
    #pragma unroll
    for (int st = 0; st < 4; ++st) acc[st] = 0.f;
    int arow = w * 16 + r16;
    #pragma unroll
    for (int kk = 0; kk < 4; ++kk) {
        v8s af = *(const v8s*)(Ab + arow * 136 + kk * 32 + quad * 8);
        #pragma unroll
        for (int st = 0; st < 4; ++st) {
            v8s bfr = *(const v8s*)(Bb + (st * 16 + r16) * 136 + kk * 32 + quad * 8);
            acc[st] = __builtin_amdgcn_mfma_f32_16x16x32_bf16(af, bfr, acc[st], 0, 0, 0);
        }
    }
    // acc -> Obuf (wave w writes only rows [w*16, w*16+16) == bytes it read of Ab)
    #pragma unroll
    for (int st = 0; st < 4; ++st)
        #pragma unroll
        for (int reg = 0; reg < 4; ++reg)
            Obuf[(w * 16 + quad * 4 + reg) * 68 + st * 16 + r16] = acc[st][reg];
    __syncthreads();

    // ---- epilogue: +U1[i] +U2[j] +(i==j)DG, leaky relu, mask, coalesced f4 store ----
    int srow = (n * NN + i) * CC;
    float4 u1 = *(const float4*)(ws + OFF_U1 + srow + c * 4);
    float4 dg = *(const float4*)(ws + OFF_DG + srow + c * 4);
    #pragma unroll
    for (int e = 0; e < 4; ++e) {
        int p = e * 16 + tp;
        int j = j0 + p;
        float4 v = *(const float4*)(Obuf + p * 68 + c * 4);
        float4 u2 = *(const float4*)(ws + OFF_U2 + (n * NN + j) * CC + c * 4);
        v.x += u1.x + u2.x; v.y += u1.y + u2.y; v.z += u1.z + u2.z; v.w += u1.w + u2.w;
        if (j == i) { v.x += dg.x; v.y += dg.y; v.z += dg.z; v.w += dg.w; }
        v.x = v.x > 0.f ? v.x : 0.01f * v.x;
        v.y = v.y > 0.f ? v.y : 0.01f * v.y;
        v.z = v.z > 0.f ? v.z : 0.01f * v.z;
        v.w = v.w > 0.f ? v.w : 0.01f * v.w;
        float m = mask[((size_t)(n * NN + i)) * NN + j];
        v.x *= m; v.y *= m; v.z *= m; v.w *= m;
        *(float4*)(out + (((size_t)(n * NN + i)) * NN + j) * CC + c * 4) = v;
    }
}

// ---------------------------------------------------------------------------
extern "C" void kernel_launch(void* const* d_in, const int* in_sizes, int n_in,
                              void* d_out, int out_size, void* d_ws, size_t ws_size,
                              hipStream_t stream) {
    const float* inputs = (const float*)d_in[0];
    const float* mask   = (const float*)d_in[1];
    // d_in[2] = nobj (unused by the reference computation)
    const float* c00 = (const float*)d_in[3];
    const float* c01 = (const float*)d_in[4];
    const float* c10 = (const float*)d_in[5];
    const float* c11 = (const float*)d_in[6];
    const float* bias  = (const float*)d_in[7];
    const float* dbias = (const float*)d_in[8];
    float* out = (float*)d_out;
    float* ws = (float*)d_ws;

    k_coefs <<<272, 256, 0, stream>>>(c00, c01, c10, c11, ws);
    k_reduce<<<512, 256, 0, stream>>>(inputs, ws);
    k_traces<<<8, 256, 0, stream>>>(ws);
    k_uv    <<<256, 64, 0, stream>>>(bias, dbias, ws);
    k_main  <<<2048, 256, 0, stream>>>(inputs, mask, ws, out);
}

// Round 3
// 136.888 us; speedup vs baseline: 2.0074x; 1.1034x over previous
//
#include <hip/hip_runtime.h>

// Problem constants (fixed by reference)
#define BB 8
#define NN 128
#define CC 64
static constexpr float INV_A = 1.0f / 49.0f;   // average_nobj = 49.0

// Workspace layout (float offsets)
#define OFF_C    0           // C[b][d][s], 15*64*64 fp32 (for k_uv)
#define OFF_CB   61440       // Cb bf16 [s][k=128]: k<64 -> C3[d][s], k>=64 -> C4[d][s]
#define OFF_RS   65536       // rowsum/A  [n][i][d]
#define OFF_CS   131072      // colsum/A  [n][j][d]
#define OFF_DV   196608      // diag      [n][i][d]
#define OFF_U1   263168      // U1 + S + bias      [n][i][s]
#define OFF_U2   328704      // U2                 [n][j][s]
#define OFF_DG   394240      // diag term + dbias  [n][i][s]

typedef __attribute__((ext_vector_type(8))) short v8s;
typedef __attribute__((ext_vector_type(4))) float v4f;

// pack two fp32 -> one dword of two bf16 (round-half-up; err <= 2^-9 rel)
static __device__ inline unsigned pack2bf(float a, float b) {
    union { float f; unsigned u; } ua, ub; ua.f = a; ub.f = b;
    return ((ua.u + 0x8000u) >> 16) | ((ub.u + 0x8000u) & 0xffff0000u);
}
static __device__ inline unsigned short f2bf(float a) {
    union { float f; unsigned u; } ua; ua.f = a;
    return (unsigned short)((ua.u + 0x8000u) >> 16);
}

// ---------------------------------------------------------------------------
// K_pre: blocks [0,512): row/col sums + diagonal capture.
//        blocks [512,784): coefficient tables (fp32 C for k_uv, bf16 Cb for k_main).
__global__ void k_pre(const float* __restrict__ in,
                      const float* __restrict__ c00, const float* __restrict__ c01,
                      const float* __restrict__ c10, const float* __restrict__ c11,
                      float* __restrict__ ws) {
    if (blockIdx.x >= 512) {
        int idx = (blockIdx.x - 512) * 256 + threadIdx.x;
        if (idx < 15 * 4096) {
            int b = idx >> 12; int r = idx & 4095; int d = r >> 6; int s = r & 63;
            ws[OFF_C + idx] = c00[d * 15 + b] * c10[d * 64 + s] + c01[s * 15 + b] * c11[d * 64 + s];
        } else if (idx < 15 * 4096 + 8192) {
            int k = idx - 15 * 4096;
            int which = k >> 12;           // 0 -> b=3 (identity), 1 -> b=4 (transpose)
            int r = k & 4095; int s = r >> 6; int d = r & 63;
            int b = 3 + which;
            float v = c00[d * 15 + b] * c10[d * 64 + s] + c01[s * 15 + b] * c11[d * 64 + s];
            unsigned short* cb = (unsigned short*)(ws + OFF_CB);
            cb[s * 128 + which * 64 + d] = f2bf(v);
        }
        return;
    }
    __shared__ float4 part[4][4][16];
    int mode = blockIdx.x >> 8;            // 0 rowsum, 1 colsum
    int bb = blockIdx.x & 255;
    int n = bb >> 5; int g0 = (bb & 31) * 4;
    int t = threadIdx.x;
    int q = t >> 6; int ii = (t >> 4) & 3; int d4 = t & 15;
    float4 acc = make_float4(0.f, 0.f, 0.f, 0.f);
    if (mode == 0) {
        int i = g0 + ii;
        float4 dvv = acc; bool hd = false;
        const float* base = in + ((size_t)(n * NN + i)) * NN * CC + d4 * 4;
        for (int j = q * 32; j < q * 32 + 32; ++j) {
            float4 v = *(const float4*)(base + (size_t)j * CC);
            acc.x += v.x; acc.y += v.y; acc.z += v.z; acc.w += v.w;
            if (j == i) { dvv = v; hd = true; }
        }
        if (hd) *(float4*)(ws + OFF_DV + ((size_t)(n * NN + i)) * CC + d4 * 4) = dvv;
    } else {
        int j = g0 + ii;
        for (int i = q * 32; i < q * 32 + 32; ++i) {
            float4 v = *(const float4*)(in + (((size_t)(n * NN + i)) * NN + j) * CC + d4 * 4);
            acc.x += v.x; acc.y += v.y; acc.z += v.z; acc.w += v.w;
        }
    }
    part[q][ii][d4] = acc;
    __syncthreads();
    if (t < 64) {
        int i2 = t >> 4; int dd = t & 15;
        float4 a = part[0][i2][dd], b = part[1][i2][dd], c = part[2][i2][dd], d = part[3][i2][dd];
        float4 s;
        s.x = (a.x + b.x + c.x + d.x) * INV_A;
        s.y = (a.y + b.y + c.y + d.y) * INV_A;
        s.z = (a.z + b.z + c.z + d.z) * INV_A;
        s.w = (a.w + b.w + c.w + d.w) * INV_A;
        *(float4*)(ws + (mode ? OFF_CS : OFF_RS) + ((size_t)(n * NN + g0 + i2)) * CC + dd * 4) = s;
    }
}

// ---------------------------------------------------------------------------
// K_uv: fused trace/allsum + broadcast-term GEMMs.
// Block = (n, 4 i-rows), 256 threads.
// Phase 1: trace/A, allsum/A^2 for this n (redundant per block, L2-hot reads).
// Phase 2: d-loop split 4-way across waves (q = t>>6 owns d in [q*16,q*16+16)),
//          cross-wave LDS reduction at the end.
__global__ __launch_bounds__(256, 4) void k_uv(const float* __restrict__ bias,
                                               const float* __restrict__ dbias,
                                               float* __restrict__ ws) {
    __shared__ float trL[64], asL[64];
    __shared__ float pU1[4][4][64], pU2[4][4][64], pDG[4][4][64];
    __shared__ float pS[4][64], pDGc[4][64];
    int n = blockIdx.x >> 5; int i0 = (blockIdx.x & 31) * 4;
    int t = threadIdx.x;
    int s = t & 63; int q = t >> 6;

    // ---- phase 1: tr[d], as[d] for this n ----
    {
        float tr = 0.f, as = 0.f;
        #pragma unroll 4
        for (int e = 0; e < 32; ++e) {
            int i = q * 32 + e;
            tr += ws[OFF_DV + ((size_t)(n * NN + i)) * CC + s];
            as += ws[OFF_RS + ((size_t)(n * NN + i)) * CC + s];
        }
        pS[q][s] = tr; pDGc[q][s] = as;
        __syncthreads();
        if (t < 64) {
            trL[t] = (pS[0][t] + pS[1][t] + pS[2][t] + pS[3][t]) * INV_A;
            asL[t] = (pDGc[0][t] + pDGc[1][t] + pDGc[2][t] + pDGc[3][t]) * INV_A;
        }
        __syncthreads();
    }

    // ---- phase 2: partial sums over this wave's 16 d's ----
    const float* C = ws + OFF_C;
    float aU1[4] = {0, 0, 0, 0}, aU2[4] = {0, 0, 0, 0}, aDG[4] = {0, 0, 0, 0};
    float aS = 0.f, aDGc = 0.f;
    #pragma unroll
    for (int c4 = 0; c4 < 4; ++c4) {
        int dc = q * 4 + c4;
        float tr4[4], as4[4], dv4[4][4], rs4[4][4], cs4[4][4];
        #pragma unroll
        for (int k = 0; k < 4; ++k) { tr4[k] = trL[dc * 4 + k]; as4[k] = asL[dc * 4 + k]; }
        #pragma unroll
        for (int ii = 0; ii < 4; ++ii) {
            size_t ro = ((size_t)(n * NN + i0 + ii)) * CC + dc * 4;
            float4 v = *(const float4*)(ws + OFF_DV + ro);
            dv4[ii][0] = v.x; dv4[ii][1] = v.y; dv4[ii][2] = v.z; dv4[ii][3] = v.w;
            float4 r = *(const float4*)(ws + OFF_RS + ro);
            rs4[ii][0] = r.x; rs4[ii][1] = r.y; rs4[ii][2] = r.z; rs4[ii][3] = r.w;
            float4 c = *(const float4*)(ws + OFF_CS + ro);
            cs4[ii][0] = c.x; cs4[ii][1] = c.y; cs4[ii][2] = c.z; cs4[ii][3] = c.w;
        }
        #pragma unroll
        for (int k = 0; k < 4; ++k) {
            int d = dc * 4 + k;
            const float* Cd = C + d * 64 + s;
            float c0 = Cd[0 * 4096], c1 = Cd[1 * 4096], c2 = Cd[2 * 4096];
            float c5 = Cd[5 * 4096], c6 = Cd[6 * 4096], c7 = Cd[7 * 4096];
            float c8 = Cd[8 * 4096], c9 = Cd[9 * 4096], c10v = Cd[10 * 4096];
            float c11v = Cd[11 * 4096], c12v = Cd[12 * 4096];
            float c13 = Cd[13 * 4096], c14 = Cd[14 * 4096];
            aS += c13 * tr4[k] + c14 * as4[k];
            aDGc += c7 * tr4[k] + c8 * as4[k];
            #pragma unroll
            for (int ii = 0; ii < 4; ++ii) {
                aU1[ii] += c1 * dv4[ii][k] + c9 * rs4[ii][k] + c11v * cs4[ii][k];
                aU2[ii] += c2 * dv4[ii][k] + c10v * rs4[ii][k] + c12v * cs4[ii][k];
                aDG[ii] += c0 * dv4[ii][k] + c5 * rs4[ii][k] + c6 * cs4[ii][k];
            }
        }
    }
    #pragma unroll
    for (int ii = 0; ii < 4; ++ii) {
        pU1[q][ii][s] = aU1[ii]; pU2[q][ii][s] = aU2[ii]; pDG[q][ii][s] = aDG[ii];
    }
    pS[q][s] = aS; pDGc[q][s] = aDGc;
    __syncthreads();

    // ---- final cross-wave reduce: thread (fi = t>>6, s = t&63) ----
    int fi = q;
    float u1 = pU1[0][fi][s] + pU1[1][fi][s] + pU1[2][fi][s] + pU1[3][fi][s];
    float u2 = pU2[0][fi][s] + pU2[1][fi][s] + pU2[2][fi][s] + pU2[3][fi][s];
    float dg = pDG[0][fi][s] + pDG[1][fi][s] + pDG[2][fi][s] + pDG[3][fi][s];
    float aSt = pS[0][s] + pS[1][s] + pS[2][s] + pS[3][s];
    float aDGct = pDGc[0][s] + pDGc[1][s] + pDGc[2][s] + pDGc[3][s];
    size_t row = ((size_t)(n * NN + i0 + fi)) * CC + s;
    ws[OFF_U1 + row] = u1 + aSt + bias[s];
    ws[OFF_U2 + row] = u2;
    ws[OFF_DG + row] = dg + aDGct + dbias[s];
}

// ---------------------------------------------------------------------------
// K_main: MFMA kernel. Block = (n, i, j-half): 64 pixels x 64 s, K=128.
// A[p][k] bf16 LDS: k<64 = x[n,i,j0+p,:], k>=64 = x[n,j0+p,i,:].
// B[s][k] bf16 LDS. Obuf (fp32 64x68) ALIASES Ab: wave w's Obuf writes depend
// on its MFMA results, which consume all its Ab reads -> safe. 34 KB LDS
// -> 4 blocks/CU.
__global__ __launch_bounds__(256, 4) void k_main(
        const float* __restrict__ in, const float* __restrict__ mask,
        const float* __restrict__ ws, float* __restrict__ out) {
    __shared__ __align__(16) unsigned char smem[34816];
    unsigned short* Ab = (unsigned short*)smem;            // 64 x 136 bf16
    unsigned short* Bb = (unsigned short*)(smem + 17408);  // 64 x 136 bf16
    float* Obuf = (float*)smem;                            // 64 x 68 fp32, aliases Ab

    int blk = blockIdx.x;
    int n = blk >> 8; int rem = blk & 255; int i = rem >> 1; int j0 = (rem & 1) * 64;
    int t = threadIdx.x;
    int tp = t >> 4; int c = t & 15;

    // ---- stage B: 64x128 bf16 from ws Cb (16 KB, L2-hot) ----
    const unsigned short* cb = (const unsigned short*)(ws + OFF_CB);
    #pragma unroll
    for (int e = 0; e < 4; ++e) {
        int s = e * 16 + tp;
        float4 v = *(const float4*)(cb + s * 128 + c * 8);     // raw 16B copy
        *(float4*)((unsigned char*)(Bb + s * 136 + c * 8)) = v;
    }
    // ---- stage A row-half: x[n,i,j0..j0+64,:] fp32 -> bf16 ----
    {
        const float* src = in + (((size_t)(n * NN + i)) * NN + j0) * CC;
        #pragma unroll
        for (int e = 0; e < 4; ++e) {
            int p = e * 16 + tp;
            float4 v = *(const float4*)(src + (size_t)p * CC + c * 4);
            uint2 pk; pk.x = pack2bf(v.x, v.y); pk.y = pack2bf(v.z, v.w);
            *(uint2*)(Ab + p * 136 + c * 4) = pk;
        }
    }
    // ---- stage A col-half: x[n,j0+p,i,:] fp32 -> bf16 ----
    #pragma unroll
    for (int e = 0; e < 4; ++e) {
        int p = e * 16 + tp;
        const float* src = in + (((size_t)(n * NN + (j0 + p))) * NN + i) * CC;
        float4 v = *(const float4*)(src + c * 4);
        uint2 pk; pk.x = pack2bf(v.x, v.y); pk.y = pack2bf(v.z, v.w);
        *(uint2*)(Ab + p * 136 + 64 + c * 4) = pk;
    }
    __syncthreads();

    // ---- MFMA compute ----
    int w = t >> 6; int l = t & 63;
    int r16 = l & 15; int quad = l >> 4;
    v4f acc[4];
    #pragma unroll
    for (int st = 0; st < 4; ++st) acc[st] = 0.f;
    int arow = w * 16 + r16;
    #pragma unroll
    for (int kk = 0; kk < 4; ++kk) {
        v8s af = *(const v8s*)(Ab + arow * 136 + kk * 32 + quad * 8);
        #pragma unroll
        for (int st = 0; st < 4; ++st) {
            v8s bfr = *(const v8s*)(Bb + (st * 16 + r16) * 136 + kk * 32 + quad * 8);
            acc[st] = __builtin_amdgcn_mfma_f32_16x16x32_bf16(af, bfr, acc[st], 0, 0, 0);
        }
    }
    // acc -> Obuf (wave w writes only rows [w*16, w*16+16), which only it read)
    #pragma unroll
    for (int st = 0; st < 4; ++st)
        #pragma unroll
        for (int reg = 0; reg < 4; ++reg)
            Obuf[(w * 16 + quad * 4 + reg) * 68 + st * 16 + r16] = acc[st][reg];
    __syncthreads();

    // ---- epilogue: +U1[i] +U2[j] +(i==j)DG, leaky relu, mask, f4 store ----
    int srow = (n * NN + i) * CC;
    float4 u1 = *(const float4*)(ws + OFF_U1 + srow + c * 4);
    float4 dg = *(const float4*)(ws + OFF_DG + srow + c * 4);
    #pragma unroll
    for (int e = 0; e < 4; ++e) {
        int p = e * 16 + tp;
        int j = j0 + p;
        float4 v = *(const float4*)(Obuf + p * 68 + c * 4);
        float4 u2 = *(const float4*)(ws + OFF_U2 + (n * NN + j) * CC + c * 4);
        v.x += u1.x + u2.x; v.y += u1.y + u2.y; v.z += u1.z + u2.z; v.w += u1.w + u2.w;
        if (j == i) { v.x += dg.x; v.y += dg.y; v.z += dg.z; v.w += dg.w; }
        v.x = v.x > 0.f ? v.x : 0.01f * v.x;
        v.y = v.y > 0.f ? v.y : 0.01f * v.y;
        v.z = v.z > 0.f ? v.z : 0.01f * v.z;
        v.w = v.w > 0.f ? v.w : 0.01f * v.w;
        float m = mask[((size_t)(n * NN + i)) * NN + j];
        v.x *= m; v.y *= m; v.z *= m; v.w *= m;
        *(float4*)(out + (((size_t)(n * NN + i)) * NN + j) * CC + c * 4) = v;
    }
}

// ---------------------------------------------------------------------------
extern "C" void kernel_launch(void* const* d_in, const int* in_sizes, int n_in,
                              void* d_out, int out_size, void* d_ws, size_t ws_size,
                              hipStream_t stream) {
    const float* inputs = (const float*)d_in[0];
    const float* mask   = (const float*)d_in[1];
    // d_in[2] = nobj (unused by the reference computation)
    const float* c00 = (const float*)d_in[3];
    const float* c01 = (const float*)d_in[4];
    const float* c10 = (const float*)d_in[5];
    const float* c11 = (const float*)d_in[6];
    const float* bias  = (const float*)d_in[7];
    const float* dbias = (const float*)d_in[8];
    float* out = (float*)d_out;
    float* ws = (float*)d_ws;

    k_pre <<<784, 256, 0, stream>>>(inputs, c00, c01, c10, c11, ws);
    k_uv  <<<256, 256, 0, stream>>>(bias, dbias, ws);
    k_main<<<2048, 256, 0, stream>>>(inputs, mask, ws, out);
}

// Round 4
// 134.355 us; speedup vs baseline: 2.0452x; 1.0189x over previous
//
#include <hip/hip_runtime.h>

// Problem constants (fixed by reference)
#define BB 8
#define NN 128
#define CC 64
static constexpr float INV_A = 1.0f / 49.0f;   // average_nobj = 49.0

// Workspace layout (float offsets)
#define OFF_C    0           // C[b][d][s], 15*64*64 fp32 (for k_uv)
#define OFF_CB   61440       // Cb bf16 [s][k=128]: k<64 -> C3[d][s], k>=64 -> C4[d][s]
#define OFF_RS   65536       // rowsum/A  [n][i][d]
#define OFF_CS   131072      // colsum/A  [n][j][d]
#define OFF_DV   196608      // diag      [n][i][d]
#define OFF_U1   263168      // U1 + S + bias      [n][i][s]
#define OFF_U2   328704      // U2                 [n][j][s]
#define OFF_DG   394240      // diag term + dbias  [n][i][s]
#define OFF_XT   459776      // xbT bf16 [n][j][i][d] = x[n,i,j,d]  (8.4M bf16)

typedef __attribute__((ext_vector_type(8))) short v8s;
typedef __attribute__((ext_vector_type(4))) float v4f;

// pack two fp32 -> one dword of two bf16 (round-half-up; err <= 2^-9 rel)
static __device__ inline unsigned pack2bf(float a, float b) {
    union { float f; unsigned u; } ua, ub; ua.f = a; ub.f = b;
    return ((ua.u + 0x8000u) >> 16) | ((ub.u + 0x8000u) & 0xffff0000u);
}
static __device__ inline unsigned short f2bf(float a) {
    union { float f; unsigned u; } ua; ua.f = a;
    return (unsigned short)((ua.u + 0x8000u) >> 16);
}

// ---------------------------------------------------------------------------
// K_pre: blocks [0,512): row/col sums + diagonal capture; colsum pass also
//        emits the bf16 transposed copy xbT[n][j][i][d] for k_main.
//        blocks [512,784): coefficient tables (fp32 C for k_uv, bf16 Cb).
__global__ void k_pre(const float* __restrict__ in,
                      const float* __restrict__ c00, const float* __restrict__ c01,
                      const float* __restrict__ c10, const float* __restrict__ c11,
                      float* __restrict__ ws) {
    if (blockIdx.x >= 512) {
        int idx = (blockIdx.x - 512) * 256 + threadIdx.x;
        if (idx < 15 * 4096) {
            int b = idx >> 12; int r = idx & 4095; int d = r >> 6; int s = r & 63;
            ws[OFF_C + idx] = c00[d * 15 + b] * c10[d * 64 + s] + c01[s * 15 + b] * c11[d * 64 + s];
        } else if (idx < 15 * 4096 + 8192) {
            int k = idx - 15 * 4096;
            int which = k >> 12;           // 0 -> b=3 (identity), 1 -> b=4 (transpose)
            int r = k & 4095; int s = r >> 6; int d = r & 63;
            int b = 3 + which;
            float v = c00[d * 15 + b] * c10[d * 64 + s] + c01[s * 15 + b] * c11[d * 64 + s];
            unsigned short* cb = (unsigned short*)(ws + OFF_CB);
            cb[s * 128 + which * 64 + d] = f2bf(v);
        }
        return;
    }
    __shared__ float4 part[4][4][16];
    int mode = blockIdx.x >> 8;            // 0 rowsum, 1 colsum(+transpose emit)
    int bb = blockIdx.x & 255;
    int n = bb >> 5; int g0 = (bb & 31) * 4;
    int t = threadIdx.x;
    int q = t >> 6; int ii = (t >> 4) & 3; int d4 = t & 15;
    float4 acc = make_float4(0.f, 0.f, 0.f, 0.f);
    if (mode == 0) {
        int i = g0 + ii;
        float4 dvv = acc; bool hd = false;
        const float* base = in + ((size_t)(n * NN + i)) * NN * CC + d4 * 4;
        for (int j = q * 32; j < q * 32 + 32; ++j) {
            float4 v = *(const float4*)(base + (size_t)j * CC);
            acc.x += v.x; acc.y += v.y; acc.z += v.z; acc.w += v.w;
            if (j == i) { dvv = v; hd = true; }
        }
        if (hd) *(float4*)(ws + OFF_DV + ((size_t)(n * NN + i)) * CC + d4 * 4) = dvv;
    } else {
        int j = g0 + ii;
        unsigned short* xT = (unsigned short*)(ws + OFF_XT);
        for (int i = q * 32; i < q * 32 + 32; ++i) {
            float4 v = *(const float4*)(in + (((size_t)(n * NN + i)) * NN + j) * CC + d4 * 4);
            acc.x += v.x; acc.y += v.y; acc.z += v.z; acc.w += v.w;
            uint2 pk; pk.x = pack2bf(v.x, v.y); pk.y = pack2bf(v.z, v.w);
            *(uint2*)(xT + (((size_t)(n * NN + j)) * NN + i) * CC + d4 * 4) = pk;
        }
    }
    part[q][ii][d4] = acc;
    __syncthreads();
    if (t < 64) {
        int i2 = t >> 4; int dd = t & 15;
        float4 a = part[0][i2][dd], b = part[1][i2][dd], c = part[2][i2][dd], d = part[3][i2][dd];
        float4 s;
        s.x = (a.x + b.x + c.x + d.x) * INV_A;
        s.y = (a.y + b.y + c.y + d.y) * INV_A;
        s.z = (a.z + b.z + c.z + d.z) * INV_A;
        s.w = (a.w + b.w + c.w + d.w) * INV_A;
        *(float4*)(ws + (mode ? OFF_CS : OFF_RS) + ((size_t)(n * NN + g0 + i2)) * CC + dd * 4) = s;
    }
}

// ---------------------------------------------------------------------------
// K_uv: fused trace/allsum + broadcast-term GEMMs (unchanged from R3).
__global__ __launch_bounds__(256, 4) void k_uv(const float* __restrict__ bias,
                                               const float* __restrict__ dbias,
                                               float* __restrict__ ws) {
    __shared__ float trL[64], asL[64];
    __shared__ float pU1[4][4][64], pU2[4][4][64], pDG[4][4][64];
    __shared__ float pS[4][64], pDGc[4][64];
    int n = blockIdx.x >> 5; int i0 = (blockIdx.x & 31) * 4;
    int t = threadIdx.x;
    int s = t & 63; int q = t >> 6;

    {
        float tr = 0.f, as = 0.f;
        #pragma unroll 4
        for (int e = 0; e < 32; ++e) {
            int i = q * 32 + e;
            tr += ws[OFF_DV + ((size_t)(n * NN + i)) * CC + s];
            as += ws[OFF_RS + ((size_t)(n * NN + i)) * CC + s];
        }
        pS[q][s] = tr; pDGc[q][s] = as;
        __syncthreads();
        if (t < 64) {
            trL[t] = (pS[0][t] + pS[1][t] + pS[2][t] + pS[3][t]) * INV_A;
            asL[t] = (pDGc[0][t] + pDGc[1][t] + pDGc[2][t] + pDGc[3][t]) * INV_A;
        }
        __syncthreads();
    }

    const float* C = ws + OFF_C;
    float aU1[4] = {0, 0, 0, 0}, aU2[4] = {0, 0, 0, 0}, aDG[4] = {0, 0, 0, 0};
    float aS = 0.f, aDGc = 0.f;
    #pragma unroll
    for (int c4 = 0; c4 < 4; ++c4) {
        int dc = q * 4 + c4;
        float tr4[4], as4[4], dv4[4][4], rs4[4][4], cs4[4][4];
        #pragma unroll
        for (int k = 0; k < 4; ++k) { tr4[k] = trL[dc * 4 + k]; as4[k] = asL[dc * 4 + k]; }
        #pragma unroll
        for (int ii = 0; ii < 4; ++ii) {
            size_t ro = ((size_t)(n * NN + i0 + ii)) * CC + dc * 4;
            float4 v = *(const float4*)(ws + OFF_DV + ro);
            dv4[ii][0] = v.x; dv4[ii][1] = v.y; dv4[ii][2] = v.z; dv4[ii][3] = v.w;
            float4 r = *(const float4*)(ws + OFF_RS + ro);
            rs4[ii][0] = r.x; rs4[ii][1] = r.y; rs4[ii][2] = r.z; rs4[ii][3] = r.w;
            float4 c = *(const float4*)(ws + OFF_CS + ro);
            cs4[ii][0] = c.x; cs4[ii][1] = c.y; cs4[ii][2] = c.z; cs4[ii][3] = c.w;
        }
        #pragma unroll
        for (int k = 0; k < 4; ++k) {
            int d = dc * 4 + k;
            const float* Cd = C + d * 64 + s;
            float c0 = Cd[0 * 4096], c1 = Cd[1 * 4096], c2 = Cd[2 * 4096];
            float c5 = Cd[5 * 4096], c6 = Cd[6 * 4096], c7 = Cd[7 * 4096];
            float c8 = Cd[8 * 4096], c9 = Cd[9 * 4096], c10v = Cd[10 * 4096];
            float c11v = Cd[11 * 4096], c12v = Cd[12 * 4096];
            float c13 = Cd[13 * 4096], c14 = Cd[14 * 4096];
            aS += c13 * tr4[k] + c14 * as4[k];
            aDGc += c7 * tr4[k] + c8 * as4[k];
            #pragma unroll
            for (int ii = 0; ii < 4; ++ii) {
                aU1[ii] += c1 * dv4[ii][k] + c9 * rs4[ii][k] + c11v * cs4[ii][k];
                aU2[ii] += c2 * dv4[ii][k] + c10v * rs4[ii][k] + c12v * cs4[ii][k];
                aDG[ii] += c0 * dv4[ii][k] + c5 * rs4[ii][k] + c6 * cs4[ii][k];
            }
        }
    }
    #pragma unroll
    for (int ii = 0; ii < 4; ++ii) {
        pU1[q][ii][s] = aU1[ii]; pU2[q][ii][s] = aU2[ii]; pDG[q][ii][s] = aDG[ii];
    }
    pS[q][s] = aS; pDGc[q][s] = aDGc;
    __syncthreads();

    int fi = q;
    float u1 = pU1[0][fi][s] + pU1[1][fi][s] + pU1[2][fi][s] + pU1[3][fi][s];
    float u2 = pU2[0][fi][s] + pU2[1][fi][s] + pU2[2][fi][s] + pU2[3][fi][s];
    float dg = pDG[0][fi][s] + pDG[1][fi][s] + pDG[2][fi][s] + pDG[3][fi][s];
    float aSt = pS[0][s] + pS[1][s] + pS[2][s] + pS[3][s];
    float aDGct = pDGc[0][s] + pDGc[1][s] + pDGc[2][s] + pDGc[3][s];
    size_t row = ((size_t)(n * NN + i0 + fi)) * CC + s;
    ws[OFF_U1 + row] = u1 + aSt + bias[s];
    ws[OFF_U2 + row] = u2;
    ws[OFF_DG + row] = dg + aDGct + dbias[s];
}

// ---------------------------------------------------------------------------
// K_main: MFMA kernel. Block = (n, i, j-half): 64 pixels x 64 s, K=128.
// A[p][k] bf16 LDS: k<64 = x[n,i,j0+p,:] (fp32 input, packed here),
//                   k>=64 = x[n,j0+p,i,:] read COALESCED from xbT bf16.
// B[s][k] bf16 LDS. Obuf aliases Ab (safe: wave-local dependency). 34 KB LDS.
__global__ __launch_bounds__(256, 4) void k_main(
        const float* __restrict__ in, const float* __restrict__ mask,
        const float* __restrict__ ws, float* __restrict__ out) {
    __shared__ __align__(16) unsigned char smem[34816];
    unsigned short* Ab = (unsigned short*)smem;            // 64 x 136 bf16
    unsigned short* Bb = (unsigned short*)(smem + 17408);  // 64 x 136 bf16
    float* Obuf = (float*)smem;                            // 64 x 68 fp32, aliases Ab

    int blk = blockIdx.x;
    int n = blk >> 8; int rem = blk & 255; int i = rem >> 1; int j0 = (rem & 1) * 64;
    int t = threadIdx.x;
    int tp = t >> 4; int c = t & 15;

    // ---- stage B: 64x128 bf16 from ws Cb (16 KB, L2-hot) ----
    const unsigned short* cb = (const unsigned short*)(ws + OFF_CB);
    #pragma unroll
    for (int e = 0; e < 4; ++e) {
        int s = e * 16 + tp;
        float4 v = *(const float4*)(cb + s * 128 + c * 8);     // raw 16B copy
        *(float4*)((unsigned char*)(Bb + s * 136 + c * 8)) = v;
    }
    // ---- stage A row-half: x[n,i,j0..j0+64,:] fp32 -> bf16 ----
    {
        const float* src = in + (((size_t)(n * NN + i)) * NN + j0) * CC;
        #pragma unroll
        for (int e = 0; e < 4; ++e) {
            int p = e * 16 + tp;
            float4 v = *(const float4*)(src + (size_t)p * CC + c * 4);
            uint2 pk; pk.x = pack2bf(v.x, v.y); pk.y = pack2bf(v.z, v.w);
            *(uint2*)(Ab + p * 136 + c * 4) = pk;
        }
    }
    // ---- stage A col-half: xbT[n][i][j0+p][:] bf16, fully coalesced 16B/lane ----
    {
        const unsigned short* xT = (const unsigned short*)(ws + OFF_XT)
                                 + (((size_t)(n * NN + i)) * NN + j0) * CC;
        #pragma unroll
        for (int r = 0; r < 2; ++r) {
            int idx = t + r * 256;
            int p = idx >> 3; int ch = idx & 7;
            float4 v = *(const float4*)(xT + (size_t)p * CC + ch * 8);  // 8 bf16
            *(float4*)((unsigned char*)(Ab + p * 136 + 64 + ch * 8)) = v;
        }
    }
    __syncthreads();

    // ---- MFMA compute ----
    int w = t >> 6; int l = t & 63;
    int r16 = l & 15; int quad = l >> 4;
    v4f acc[4];
    #pragma unroll
    for (int st = 0; st < 4; ++st) acc[st] = 0.f;
    int arow = w * 16 + r16;
    #pragma unroll
    for (int kk = 0; kk < 4; ++kk) {
        v8s af = *(const v8s*)(Ab + arow * 136 + kk * 32 + quad * 8);
        #pragma unroll
        for (int st = 0; st < 4; ++st) {
            v8s bfr = *(const v8s*)(Bb + (st * 16 + r16) * 136 + kk * 32 + quad * 8);
            acc[st] = __builtin_amdgcn_mfma_f32_16x16x32_bf16(af, bfr, acc[st], 0, 0, 0);
        }
    }
    // acc -> Obuf (wave w writes only rows [w*16, w*16+16), which only it read)
    #pragma unroll
    for (int st = 0; st < 4; ++st)
        #pragma unroll
        for (int reg = 0; reg < 4; ++reg)
            Obuf[(w * 16 + quad * 4 + reg) * 68 + st * 16 + r16] = acc[st][reg];
    __syncthreads();

    // ---- epilogue: +U1[i] +U2[j] +(i==j)DG, leaky relu, mask, f4 store ----
    int srow = (n * NN + i) * CC;
    float4 u1 = *(const float4*)(ws + OFF_U1 + srow + c * 4);
    float4 dg = *(const float4*)(ws + OFF_DG + srow + c * 4);
    #pragma unroll
    for (int e = 0; e < 4; ++e) {
        int p = e * 16 + tp;
        int j = j0 + p;
        float4 v = *(const float4*)(Obuf + p * 68 + c * 4);
        float4 u2 = *(const float4*)(ws + OFF_U2 + (n * NN + j) * CC + c * 4);
        v.x += u1.x + u2.x; v.y += u1.y + u2.y; v.z += u1.z + u2.z; v.w += u1.w + u2.w;
        if (j == i) { v.x += dg.x; v.y += dg.y; v.z += dg.z; v.w += dg.w; }
        v.x = v.x > 0.f ? v.x : 0.01f * v.x;
        v.y = v.y > 0.f ? v.y : 0.01f * v.y;
        v.z = v.z > 0.f ? v.z : 0.01f * v.z;
        v.w = v.w > 0.f ? v.w : 0.01f * v.w;
        float m = mask[((size_t)(n * NN + i)) * NN + j];
        v.x *= m; v.y *= m; v.z *= m; v.w *= m;
        *(float4*)(out + (((size_t)(n * NN + i)) * NN + j) * CC + c * 4) = v;
    }
}

// ---------------------------------------------------------------------------
extern "C" void kernel_launch(void* const* d_in, const int* in_sizes, int n_in,
                              void* d_out, int out_size, void* d_ws, size_t ws_size,
                              hipStream_t stream) {
    const float* inputs = (const float*)d_in[0];
    const float* mask   = (const float*)d_in[1];
    // d_in[2] = nobj (unused by the reference computation)
    const float* c00 = (const float*)d_in[3];
    const float* c01 = (const float*)d_in[4];
    const float* c10 = (const float*)d_in[5];
    const float* c11 = (const float*)d_in[6];
    const float* bias  = (const float*)d_in[7];
    const float* dbias = (const float*)d_in[8];
    float* out = (float*)d_out;
    float* ws = (float*)d_ws;

    k_pre <<<784, 256, 0, stream>>>(inputs, c00, c01, c10, c11, ws);
    k_uv  <<<256, 256, 0, stream>>>(bias, dbias, ws);
    k_main<<<2048, 256, 0, stream>>>(inputs, mask, ws, out);
}